// Round 1
// baseline (96.554 us; speedup 1.0000x reference)
//
#include <hip/hip_runtime.h>
#include <math.h>

#define N_HI 192      // IMAGE_RES_OUT * IMAGE_UPSCALE
#define F_HI 128      // FREQ_RES_OUT * FREQ_UPSCALE
#define NOUT 96
#define FOUT 32

__device__ __forceinline__ float fast_exp2(float x) {
#if __has_builtin(__builtin_amdgcn_exp2f)
    return __builtin_amdgcn_exp2f(x);
#else
    return exp2f(x);
#endif
}

__global__ __launch_bounds__(256) void cube_sim_kernel(
    const float* __restrict__ p_inc, const float* __restrict__ p_rot,
    const float* __restrict__ p_lb,  const float* __restrict__ p_vs,
    const float* __restrict__ p_vmax,const float* __restrict__ p_rc,
    const float* __restrict__ p_Rd,  const float* __restrict__ p_hz,
    const float* __restrict__ freqs, float* __restrict__ out)
{
    const int jo  = blockIdx.x;
    const int io  = blockIdx.y;
    const int tid = threadIdx.x;

    __shared__ float vlos_s[4][N_HI];
    __shared__ float inten_s[4][N_HI];
    __shared__ float acc_s[4][F_HI];

    // ---- uniform scalar setup (all threads compute identical values) ----
    const float FOV     = 500.0f;
    const float C_KMS   = 299792.458f;
    const float F_REST  = 230.538f;
    const float LOG2E   = 1.4426950408889634f;

    const float inc    = *p_inc;
    const float rot    = *p_rot;
    const float lb     = *p_lb;
    const float vshift = *p_vs;
    const float vmax   = *p_vmax;
    const float rc     = *p_rc;
    const float Rd     = *p_Rd;
    const float hz     = *p_hz;
    const float f0     = freqs[0];
    const float f_last = freqs[FOUT - 1];

    const float cr = cosf(rot), sr = sinf(rot);
    const float ci = cosf(inc), si = sinf(inc);

    const float dx         = 2.0f * FOV / (float)(N_HI - 1);
    const float pixelscale = 2.0f * FOV / (float)N_HI;
    const float Rmin       = 0.1f * pixelscale;
    const float rc2pm      = rc * rc + Rmin * Rmin;   // r_c^2 + Rmin^2
    const float sig_sq     = lb * lb;
    const float c2         = (0.5f / sig_sq) * LOG2E; // exponent coeff (log2 space)
    const float kR         = LOG2E / Rd;
    const float kz         = 0.5f * LOG2E / (hz * hz);

    const float fstep = (f_last - f0) / (float)(F_HI - 1);
    const float vlA   = C_KMS * (1.0f - f0 / F_REST) - vshift;  // vlab(0)
    const float vlB   = -C_KMS * fstep / F_REST;                // vlab step per channel

    // ---- phase 1: per-voxel v_los and intensity into LDS ----
    // 4 columns (iu,ju in 2x2) x 192 k-voxels = 768 tasks
    for (int t = tid; t < 4 * N_HI; t += 256) {
        const int col = t / N_HI;
        const int k   = t - col * N_HI;
        const int i   = (io << 1) + (col >> 1);
        const int j   = (jo << 1) + (col & 1);

        const float x = -FOV + dx * (float)i;
        const float y = -FOV + dx * (float)j;
        const float z = -FOV + dx * (float)k;

        const float rx = cr * x - sr * y;     // rot_x (i,j only)
        const float y1 = sr * x + cr * y;
        const float ry = ci * y1 - si * z;    // rot_y
        const float rz = si * y1 + ci * z;    // rot_z

        const float R  = sqrtf(rx * rx + ry * ry);
        const float Rc = fmaxf(R, Rmin);      // mimic jnp.interp left clamp
        const float va = vmax * Rc * __frsqrt_rn(Rc * Rc + rc2pm);
        // v_los = -si * v_abs * cos(theta),  cos(theta) = rot_x / R
        const float vlos = -si * va * rx / fmaxf(R, 1e-20f);
        // intensity = exp(-R/Rd - 0.5*(rz/hz)^2)   (in log2 space)
        const float I = fast_exp2(-(R * kR + rz * rz * kz));

        vlos_s[col][k]  = vlos;
        inten_s[col][k] = I;
    }
    __syncthreads();

    // ---- phase 2: channel accumulation. wave w -> column w, lane -> f and f+64 ----
    const int col  = tid >> 6;
    const int lane = tid & 63;
    const float vlab0 = vlA + vlB * (float)lane;
    const float vlab1 = vlA + vlB * (float)(lane + 64);

    float acc0 = 0.0f, acc1 = 0.0f;
    for (int k = 0; k < N_HI; ++k) {
        const float Ik = inten_s[col][k];
        if (Ik < 1e-7f) continue;           // wave-uniform skip (thin disk)
        const float vl = vlos_s[col][k];
        const float d0 = vlab0 - vl;
        const float d1 = vlab1 - vl;
        acc0 += Ik * fast_exp2(-(d0 * d0) * c2);
        acc1 += Ik * fast_exp2(-(d1 * d1) * c2);
    }
    acc_s[col][lane]      = acc0;
    acc_s[col][lane + 64] = acc1;
    __syncthreads();

    // ---- phase 3: reduce 4 freq-subchannels x 4 columns -> 32 outputs ----
    if (tid < FOUT) {
        float s = 0.0f;
        #pragma unroll
        for (int fu = 0; fu < 4; ++fu)
            #pragma unroll
            for (int c = 0; c < 4; ++c)
                s += acc_s[c][4 * tid + fu];
        const float norm = 1.0f / sqrtf(2.0f * 3.14159265358979f * sig_sq);
        out[tid * (NOUT * NOUT) + io * NOUT + jo] = s * norm * (1.0f / 16.0f);
    }
}

extern "C" void kernel_launch(void* const* d_in, const int* in_sizes, int n_in,
                              void* d_out, int out_size, void* d_ws, size_t ws_size,
                              hipStream_t stream) {
    const float* p_inc  = (const float*)d_in[0];
    const float* p_rot  = (const float*)d_in[1];
    const float* p_lb   = (const float*)d_in[2];
    const float* p_vs   = (const float*)d_in[3];
    const float* p_vmax = (const float*)d_in[4];
    const float* p_rc   = (const float*)d_in[5];
    const float* p_Rd   = (const float*)d_in[6];
    const float* p_hz   = (const float*)d_in[7];
    const float* freqs  = (const float*)d_in[8];
    float* out = (float*)d_out;

    dim3 grid(NOUT, NOUT);
    dim3 block(256);
    cube_sim_kernel<<<grid, block, 0, stream>>>(p_inc, p_rot, p_lb, p_vs,
                                                p_vmax, p_rc, p_Rd, p_hz,
                                                freqs, out);
}